// Round 6
// baseline (227.592 us; speedup 1.0000x reference)
//
#include <hip/hip_runtime.h>

#define BATCH 16

// ---------------------------------------------------------------------------
// 4-lane fused d+i unit (for the big level kernels).
// Unit = (p, b), lanes q=0..3. Lane q computes cell q's d-output solo, then
// owns i-vec components [4q..4q+3] as float4. Wave = 16 b x 4 q of ONE p, so
// all A loads broadcast across 16 lanes and each p's iA is read once/wave.
// ---------------------------------------------------------------------------
template <int H>
__device__ __forceinline__ float fused_di_unit4(
    const float* __restrict__ xb, int p, int q,
    const float* __restrict__ dA, const float* __restrict__ dv,
    const float* __restrict__ dw,
    const float* __restrict__ iA, const float* __restrict__ iv,
    const float* __restrict__ iw) {
  constexpr int NH = (H - 2) / 2;
  constexpr int W2 = H / 2;
  int pi = p / W2, pj = p % W2;
  int r = 2 * pi + (q >> 1), c = 2 * pj + (q & 1);
  float tcell;
  bool border = (r == 0) | (r == H - 1) | (c == 0) | (c == H - 1);
  if (border) {
    tcell = xb[r * H + c];  // d leaves borders untouched
  } else {
    int dpi = (r - 1) >> 1, dpj = (c - 1) >> 1;
    int sd = ((r - 1) & 1) * 2 + ((c - 1) & 1);
    int dp = dpi * NH + dpj;
    int R0 = 1 + 2 * dpi, C0 = 1 + 2 * dpj;
    float tt[4];
    tt[0] = xb[R0 * H + C0];
    tt[1] = xb[R0 * H + C0 + 1];
    tt[2] = xb[(R0 + 1) * H + C0];
    tt[3] = xb[(R0 + 1) * H + C0 + 1];
    const float4* Ad = (const float4*)(dA + dp * 128);  // [s][f][4][4]
    float ve[4];
#pragma unroll
    for (int i = 0; i < 4; i++) ve[i] = dv[dp * 4 + i];
#pragma unroll
    for (int s = 0; s < 4; s++) {
      float ts = tt[s], us = 1.0f - ts;
      float vn[4] = {0.f, 0.f, 0.f, 0.f};
#pragma unroll
      for (int i = 0; i < 4; i++) {
        float4 a0 = Ad[s * 8 + i];      // A0 row i
        float4 a1 = Ad[s * 8 + 4 + i];  // A1 row i
        vn[0] = fmaf(ve[i], ts * a0.x + us * a1.x, vn[0]);
        vn[1] = fmaf(ve[i], ts * a0.y + us * a1.y, vn[1]);
        vn[2] = fmaf(ve[i], ts * a0.z + us * a1.z, vn[2]);
        vn[3] = fmaf(ve[i], ts * a0.w + us * a1.w, vn[3]);
      }
#pragma unroll
      for (int i = 0; i < 4; i++) ve[i] = vn[i];
    }
    float y = 0.f;
#pragma unroll
    for (int i = 0; i < 4; i++) y = fmaf(ve[i], dw[dp * 16 + i * 4 + sd], y);
    tcell = fmaxf(y, 0.0f);
  }
  // broadcast the 4 cell values within the unit
  float t[4];
  t[0] = __shfl(tcell, 0, 4);
  t[1] = __shfl(tcell, 1, 4);
  t[2] = __shfl(tcell, 2, 4);
  t[3] = __shfl(tcell, 3, 4);
  // i-MPS (D=16): lane q owns columns 4q..4q+3
  const float* Ai = iA + p * 2048;  // [s][f][16][16]
  float4 vec = ((const float4*)(iv + p * 16))[q];
#pragma unroll
  for (int s = 0; s < 4; s++) {
    const float4* A0 = (const float4*)(Ai + s * 512);
    const float4* A1 = (const float4*)(Ai + s * 512 + 256);
    float ts = t[s], us = 1.0f - ts;
    float4 q0 = {0.f, 0.f, 0.f, 0.f};
    float4 q1 = {0.f, 0.f, 0.f, 0.f};
#pragma unroll
    for (int i = 0; i < 16; i++) {
      float comp = ((i & 3) == 0) ? vec.x
                 : ((i & 3) == 1) ? vec.y
                 : ((i & 3) == 2) ? vec.z : vec.w;
      float sv = __shfl(comp, i >> 2, 4);
      float4 a0 = A0[i * 4 + q];
      float4 a1 = A1[i * 4 + q];
      q0.x = fmaf(sv, a0.x, q0.x);
      q0.y = fmaf(sv, a0.y, q0.y);
      q0.z = fmaf(sv, a0.z, q0.z);
      q0.w = fmaf(sv, a0.w, q0.w);
      q1.x = fmaf(sv, a1.x, q1.x);
      q1.y = fmaf(sv, a1.y, q1.y);
      q1.z = fmaf(sv, a1.z, q1.z);
      q1.w = fmaf(sv, a1.w, q1.w);
    }
    vec.x = ts * q0.x + us * q1.x;
    vec.y = ts * q0.y + us * q1.y;
    vec.z = ts * q0.z + us * q1.z;
    vec.w = ts * q0.w + us * q1.w;
  }
  float4 w4 = ((const float4*)(iw + p * 16))[q];
  float partial = vec.x * w4.x + vec.y * w4.y + vec.z * w4.z + vec.w * w4.w;
  partial += __shfl_xor(partial, 1, 4);
  partial += __shfl_xor(partial, 2, 4);
  return fmaxf(partial, 0.0f);
}

// One fused level, 4-lane units. Block 256 = 64 units = 4 p x 16 b.
template <int H>
__global__ __launch_bounds__(256) void level_kernel4(
    const float* __restrict__ xin, float* __restrict__ hn,
    const float* __restrict__ dA, const float* __restrict__ dv,
    const float* __restrict__ dw, const float* __restrict__ iA,
    const float* __restrict__ iv, const float* __restrict__ iw) {
  constexpr int W2 = H / 2;
  int g = blockIdx.x * 256 + threadIdx.x;
  int q = g & 3;
  int unit = g >> 2;
  int b = unit & 15;
  int p = unit >> 4;
  const float* xb = xin + b * H * H;
  float o = fused_di_unit4<H>(xb, p, q, dA, dv, dw, iA, iv, iw);
  if (q == 0) hn[b * W2 * W2 + p] = o;
}

// ---------------------------------------------------------------------------
// 16-lane fused d+i unit (for the latency-bound tail: keeps 16 waves alive).
// ---------------------------------------------------------------------------
template <int H>
__device__ __forceinline__ float fused_di_unit(
    const float* __restrict__ xb, int p, int j,
    const float* __restrict__ dA, const float* __restrict__ dv,
    const float* __restrict__ dw,
    const float* __restrict__ iA, const float* __restrict__ iv,
    const float* __restrict__ iw) {
  constexpr int NH = (H - 2) / 2;
  constexpr int W2 = H / 2;
  int pi = p / W2, pj = p % W2;
  int sg = j >> 2, j4 = j & 3;
  int r = 2 * pi + (sg >> 1), c = 2 * pj + (sg & 1);
  float tcell;
  bool border = (r == 0) | (r == H - 1) | (c == 0) | (c == H - 1);
  if (border) {
    tcell = xb[r * H + c];
  } else {
    int dpi = (r - 1) >> 1, dpj = (c - 1) >> 1;
    int sd = ((r - 1) & 1) * 2 + ((c - 1) & 1);
    int dp = dpi * NH + dpj;
    int R0 = 1 + 2 * dpi, C0 = 1 + 2 * dpj;
    float tin = xb[(R0 + (j4 >> 1)) * H + (C0 + (j4 & 1))];
    const float* Ap = dA + dp * 128;
    float vec = dv[dp * 4 + j4];
#pragma unroll
    for (int s = 0; s < 4; s++) {
      float ts = __shfl(tin, s, 4);
      const float* A0 = Ap + s * 32;
      float q0 = 0.f, q1 = 0.f;
#pragma unroll
      for (int i = 0; i < 4; i++) {
        float sv = __shfl(vec, i, 4);
        q0 = fmaf(sv, A0[i * 4 + j4], q0);
        q1 = fmaf(sv, A0[16 + i * 4 + j4], q1);
      }
      vec = ts * q0 + (1.0f - ts) * q1;
    }
    float y = 0.f;
#pragma unroll
    for (int i = 0; i < 4; i++)
      y = fmaf(__shfl(vec, i, 4), dw[dp * 16 + i * 4 + j4], y);
    y = fmaxf(y, 0.0f);
    tcell = __shfl(y, sd, 4);
  }
  float t[4];
  t[0] = __shfl(tcell, 0, 16);
  t[1] = __shfl(tcell, 4, 16);
  t[2] = __shfl(tcell, 8, 16);
  t[3] = __shfl(tcell, 12, 16);
  const float* Ap = iA + p * 2048;
  float vec = iv[p * 16 + j];
#pragma unroll
  for (int s = 0; s < 4; s++) {
    const float* A0 = Ap + s * 512;
    float q0 = 0.f, q1 = 0.f;
#pragma unroll
    for (int i = 0; i < 16; i++) {
      float sv = __shfl(vec, i, 16);
      q0 = fmaf(sv, A0[i * 16 + j], q0);
      q1 = fmaf(sv, A0[256 + i * 16 + j], q1);
    }
    vec = t[s] * q0 + (1.0f - t[s]) * q1;
  }
  float partial = vec * iw[p * 16 + j];
#pragma unroll
  for (int off = 8; off >= 1; off >>= 1)
    partial += __shfl_xor(partial, off, 16);
  return fmaxf(partial, 0.0f);
}

// ---------------------------------------------------------------------------
// Tail: levels 4-6 + head. One WG per batch element; pyramid in LDS.
// ---------------------------------------------------------------------------
struct TailArgs {
  const float* h3;
  const float* in[21];  // d4A..fw  (d_in[19..39])
  float* out;
};

__global__ __launch_bounds__(1024) void tail_kernel(TailArgs a) {
  __shared__ float x4[256];
  __shared__ float h4[64];
  __shared__ float h5[16];
  __shared__ float h6[4];
  int b = blockIdx.x;
  int tid = threadIdx.x;
  if (tid < 256) x4[tid] = a.h3[b * 256 + tid];
  __syncthreads();
  {
    int j = tid & 15, p = tid >> 4;
    float o = fused_di_unit<16>(x4, p, j, a.in[0], a.in[1], a.in[2],
                                a.in[3], a.in[4], a.in[5]);
    if (j == 0) h4[p] = o;
  }
  __syncthreads();
  if (tid < 256) {
    int j = tid & 15, p = tid >> 4;
    float o = fused_di_unit<8>(h4, p, j, a.in[6], a.in[7], a.in[8],
                               a.in[9], a.in[10], a.in[11]);
    if (j == 0) h5[p] = o;
  }
  __syncthreads();
  if (tid < 64) {
    int j = tid & 15, p = tid >> 4;
    float o = fused_di_unit<4>(h5, p, j, a.in[12], a.in[13], a.in[14],
                               a.in[15], a.in[16], a.in[17]);
    if (j == 0) h6[p] = o;
  }
  __syncthreads();
  if (tid < 16) {
    int j = tid;
    const float* fA = a.in[18];
    const float* fv = a.in[19];
    const float* fw = a.in[20];
    float t[4] = {h6[0], h6[1], h6[2], h6[3]};
    float vec = fv[j];
#pragma unroll
    for (int s = 0; s < 4; s++) {
      const float* A0 = fA + s * 512;
      float q0 = 0.f, q1 = 0.f;
#pragma unroll
      for (int i = 0; i < 16; i++) {
        float sv = __shfl(vec, i, 16);
        q0 = fmaf(sv, A0[i * 16 + j], q0);
        q1 = fmaf(sv, A0[256 + i * 16 + j], q1);
      }
      vec = t[s] * q0 + (1.0f - t[s]) * q1;
    }
    float acc = 0.0f;
#pragma unroll
    for (int i = 0; i < 16; i++) {
      float sv = __shfl(vec, i, 16);
      float wv = (j < 10) ? fw[i * 10 + j] : 0.0f;
      acc = fmaf(sv, wv, acc);
    }
    if (j < 10) a.out[b * 10 + j] = fmaxf(acc, 0.0f);
  }
}

extern "C" void kernel_launch(void* const* d_in, const int* in_sizes, int n_in,
                              void* d_out, int out_size, void* d_ws, size_t ws_size,
                              hipStream_t stream) {
  const float* x = (const float*)d_in[0];
  float* ws = (float*)d_ws;
  float* h1 = ws;            // 16*64*64
  float* h2 = h1 + 65536;    // 16*32*32
  float* h3 = h2 + 16384;    // 16*16*16

  // blocks = W2*W2*16*4/256 = W2*W2/4
  level_kernel4<128><<<1024, 256, 0, stream>>>(
      x, h1, (const float*)d_in[1], (const float*)d_in[2],
      (const float*)d_in[3], (const float*)d_in[4], (const float*)d_in[5],
      (const float*)d_in[6]);
  level_kernel4<64><<<256, 256, 0, stream>>>(
      h1, h2, (const float*)d_in[7], (const float*)d_in[8],
      (const float*)d_in[9], (const float*)d_in[10], (const float*)d_in[11],
      (const float*)d_in[12]);
  level_kernel4<32><<<64, 256, 0, stream>>>(
      h2, h3, (const float*)d_in[13], (const float*)d_in[14],
      (const float*)d_in[15], (const float*)d_in[16], (const float*)d_in[17],
      (const float*)d_in[18]);

  TailArgs ta;
  ta.h3 = h3;
  for (int i = 0; i < 21; i++) ta.in[i] = (const float*)d_in[19 + i];
  ta.out = (float*)d_out;
  tail_kernel<<<BATCH, 1024, 0, stream>>>(ta);
}

// Round 7
// 212.685 us; speedup vs baseline: 1.0701x; 1.0701x over previous
//
#include <hip/hip_runtime.h>

#define BATCH 16

// ---------------------------------------------------------------------------
// 16-lane fused d+i unit: one group computes one i-patch output, recomputing
// the d-transform of its 4 input cells on the fly (4 lanes per cell).
// ---------------------------------------------------------------------------
template <int H>
__device__ __forceinline__ float fused_di_unit(
    const float* __restrict__ xb, int p, int j,
    const float* __restrict__ dA, const float* __restrict__ dv,
    const float* __restrict__ dw,
    const float* __restrict__ iA, const float* __restrict__ iv,
    const float* __restrict__ iw) {
  constexpr int NH = (H - 2) / 2;
  constexpr int W2 = H / 2;
  int pi = p / W2, pj = p % W2;
  int sg = j >> 2, j4 = j & 3;
  int r = 2 * pi + (sg >> 1), c = 2 * pj + (sg & 1);
  float tcell;
  bool border = (r == 0) | (r == H - 1) | (c == 0) | (c == H - 1);
  if (border) {
    tcell = xb[r * H + c];  // d leaves borders untouched
  } else {
    int dpi = (r - 1) >> 1, dpj = (c - 1) >> 1;
    int sd = ((r - 1) & 1) * 2 + ((c - 1) & 1);
    int dp = dpi * NH + dpj;
    int R0 = 1 + 2 * dpi, C0 = 1 + 2 * dpj;
    float tin = xb[(R0 + (j4 >> 1)) * H + (C0 + (j4 & 1))];
    const float* Ap = dA + dp * 128;  // [s][f][4][4]
    float vec = dv[dp * 4 + j4];
#pragma unroll
    for (int s = 0; s < 4; s++) {
      float ts = __shfl(tin, s, 4);
      const float* A0 = Ap + s * 32;
      float q0 = 0.f, q1 = 0.f;
#pragma unroll
      for (int i = 0; i < 4; i++) {
        float sv = __shfl(vec, i, 4);
        q0 = fmaf(sv, A0[i * 4 + j4], q0);
        q1 = fmaf(sv, A0[16 + i * 4 + j4], q1);
      }
      vec = ts * q0 + (1.0f - ts) * q1;
    }
    float y = 0.f;
#pragma unroll
    for (int i = 0; i < 4; i++)
      y = fmaf(__shfl(vec, i, 4), dw[dp * 16 + i * 4 + j4], y);
    y = fmaxf(y, 0.0f);
    tcell = __shfl(y, sd, 4);  // the d-output cell this i-cell needs
  }
  // broadcast the 4 cell values to all 16 lanes
  float t[4];
  t[0] = __shfl(tcell, 0, 16);
  t[1] = __shfl(tcell, 4, 16);
  t[2] = __shfl(tcell, 8, 16);
  t[3] = __shfl(tcell, 12, 16);
  // i-MPS (D=16), lane j owns component j
  const float* Ap = iA + p * 2048;  // [s][f][16][16]
  float vec = iv[p * 16 + j];
#pragma unroll
  for (int s = 0; s < 4; s++) {
    const float* A0 = Ap + s * 512;
    float q0 = 0.f, q1 = 0.f;
#pragma unroll
    for (int i = 0; i < 16; i++) {
      float sv = __shfl(vec, i, 16);
      q0 = fmaf(sv, A0[i * 16 + j], q0);
      q1 = fmaf(sv, A0[256 + i * 16 + j], q1);
    }
    vec = t[s] * q0 + (1.0f - t[s]) * q1;
  }
  float partial = vec * iw[p * 16 + j];
#pragma unroll
  for (int off = 8; off >= 1; off >>= 1)
    partial += __shfl_xor(partial, off, 16);
  return fmaxf(partial, 0.0f);
}

// ---------------------------------------------------------------------------
// One fused level. Block 256 = 16 b x 16 j of ONE p (p = blockIdx).
// Levels 1-4: H = 128, 64, 32, 16.
// ---------------------------------------------------------------------------
template <int H>
__global__ __launch_bounds__(256) void level_kernel(
    const float* __restrict__ xin, float* __restrict__ hn,
    const float* __restrict__ dA, const float* __restrict__ dv,
    const float* __restrict__ dw, const float* __restrict__ iA,
    const float* __restrict__ iv, const float* __restrict__ iw) {
  constexpr int W2 = H / 2;
  int g = blockIdx.x * 256 + threadIdx.x;
  int j = g & 15;
  int b = (g >> 4) & 15;
  int p = g >> 8;
  const float* xb = xin + b * H * H;
  float o = fused_di_unit<H>(xb, p, j, dA, dv, dw, iA, iv, iw);
  if (j == 0) hn[b * W2 * W2 + p] = o;
}

// ---------------------------------------------------------------------------
// Tail2: levels 5-6 + final head only. One WG (256 thr) per batch element.
// Level-4 is a separate wide launch now; per-WG param set is ~180 KB shared
// across the 16 WGs via L2.
// ---------------------------------------------------------------------------
struct Tail2Args {
  const float* h4;      // 16 x 8 x 8
  const float* in[15];  // d5A..fw  (d_in[25..39])
  float* out;
};

__global__ __launch_bounds__(256) void tail2_kernel(Tail2Args a) {
  __shared__ float x5[64];  // 8x8
  __shared__ float h5[16];  // 4x4
  __shared__ float h6[4];   // 2x2
  int b = blockIdx.x;
  int tid = threadIdx.x;
  if (tid < 64) x5[tid] = a.h4[b * 64 + tid];
  __syncthreads();
  // level 5: H=8 -> 16 units x 16 lanes = 256 threads
  {
    int j = tid & 15, p = tid >> 4;
    float o = fused_di_unit<8>(x5, p, j, a.in[0], a.in[1], a.in[2],
                               a.in[3], a.in[4], a.in[5]);
    if (j == 0) h5[p] = o;
  }
  __syncthreads();
  // level 6: H=4 -> 4 units -> 64 threads
  if (tid < 64) {
    int j = tid & 15, p = tid >> 4;
    float o = fused_di_unit<4>(h5, p, j, a.in[6], a.in[7], a.in[8],
                               a.in[9], a.in[10], a.in[11]);
    if (j == 0) h6[p] = o;
  }
  __syncthreads();
  // final head: flat (2x2) -> 10 classes; 16 lanes, lane j owns vec[j]
  if (tid < 16) {
    int j = tid;
    const float* fA = a.in[12];
    const float* fv = a.in[13];
    const float* fw = a.in[14];
    float t[4] = {h6[0], h6[1], h6[2], h6[3]};
    float vec = fv[j];
#pragma unroll
    for (int s = 0; s < 4; s++) {
      const float* A0 = fA + s * 512;
      float q0 = 0.f, q1 = 0.f;
#pragma unroll
      for (int i = 0; i < 16; i++) {
        float sv = __shfl(vec, i, 16);
        q0 = fmaf(sv, A0[i * 16 + j], q0);
        q1 = fmaf(sv, A0[256 + i * 16 + j], q1);
      }
      vec = t[s] * q0 + (1.0f - t[s]) * q1;
    }
    float acc = 0.0f;
#pragma unroll
    for (int i = 0; i < 16; i++) {
      float sv = __shfl(vec, i, 16);
      float wv = (j < 10) ? fw[i * 10 + j] : 0.0f;
      acc = fmaf(sv, wv, acc);
    }
    if (j < 10) a.out[b * 10 + j] = fmaxf(acc, 0.0f);
  }
}

extern "C" void kernel_launch(void* const* d_in, const int* in_sizes, int n_in,
                              void* d_out, int out_size, void* d_ws, size_t ws_size,
                              hipStream_t stream) {
  const float* x = (const float*)d_in[0];
  float* ws = (float*)d_ws;
  float* h1 = ws;            // 16*64*64 = 65536
  float* h2 = h1 + 65536;    // 16*32*32 = 16384
  float* h3 = h2 + 16384;    // 16*16*16 = 4096
  float* h4 = h3 + 4096;     // 16*8*8   = 1024

  // blocks = W2*W2 (one patch per block, 16 b x 16 j lanes)
  level_kernel<128><<<4096, 256, 0, stream>>>(
      x, h1, (const float*)d_in[1], (const float*)d_in[2],
      (const float*)d_in[3], (const float*)d_in[4], (const float*)d_in[5],
      (const float*)d_in[6]);
  level_kernel<64><<<1024, 256, 0, stream>>>(
      h1, h2, (const float*)d_in[7], (const float*)d_in[8],
      (const float*)d_in[9], (const float*)d_in[10], (const float*)d_in[11],
      (const float*)d_in[12]);
  level_kernel<32><<<256, 256, 0, stream>>>(
      h2, h3, (const float*)d_in[13], (const float*)d_in[14],
      (const float*)d_in[15], (const float*)d_in[16], (const float*)d_in[17],
      (const float*)d_in[18]);
  level_kernel<16><<<64, 256, 0, stream>>>(
      h3, h4, (const float*)d_in[19], (const float*)d_in[20],
      (const float*)d_in[21], (const float*)d_in[22], (const float*)d_in[23],
      (const float*)d_in[24]);

  Tail2Args ta;
  ta.h4 = h4;
  for (int i = 0; i < 15; i++) ta.in[i] = (const float*)d_in[25 + i];
  ta.out = (float*)d_out;
  tail2_kernel<<<BATCH, 256, 0, stream>>>(ta);
}